// Round 4
// baseline (50.848 us; speedup 1.0000x reference)
//
#include <hip/hip_runtime.h>
#include <math.h>

#define NPTS   8192
#define BITS   64
#define NCLS   101
#define TILE   128
#define NT     (NPTS / TILE)            // 64
#define NPAIRS (NT * (NT + 1) / 2)      // 2080
#define WS_CLS (3 * NPAIRS)
#define HBF_BYTES (NPTS * BITS * 2)     // 1 MiB of bf16 H
#define SCALE  0.84932184f              // sqrt(0.5 * log2(e)) -> acc = theta*log2(e)
#define LN2    0.6931471805599453

// ws layout:
//   bytes [0, 1MiB)           : Hb — bf16 H, pre-scaled by sqrt(0.5*log2 e)
//   doubles after that:
//     [0, NPAIRS)             : L2-softplus over valid i<j     (x ln2 deferred)
//     [NPAIRS, 2*NPAIRS)      : L2-softplus over same-class    (x ln2 deferred)
//     [2*NPAIRS, 3*NPAIRS)    : t = theta*log2e over same-class(x ln2 deferred)
//     [WS_CLS, WS_CLS+NPAIRS) : cls NLL partials

typedef short    bf16x8   __attribute__((ext_vector_type(8)));
typedef unsigned short ushort8v __attribute__((ext_vector_type(8)));
typedef float    f32x16   __attribute__((ext_vector_type(16)));

__device__ __forceinline__ unsigned short f2bf(float f) {
    unsigned int u = __float_as_uint(f);
    u += 0x7FFFu + ((u >> 16) & 1u);     // RNE (inputs finite)
    return (unsigned short)(u >> 16);
}

// ---------------------------------------------------------------------------
// Kernel A: one-shot fp32 -> scaled bf16 conversion of H (512K elements).
// ---------------------------------------------------------------------------
__global__ __launch_bounds__(256) void conv_kernel(const float* __restrict__ H,
                                                   unsigned short* __restrict__ Hb) {
    const size_t t = blockIdx.x * 256 + threadIdx.x;   // 65536 threads x 8 elems
    const float4 f0 = *(const float4*)(H + t * 8);
    const float4 f1 = *(const float4*)(H + t * 8 + 4);
    ushort8v v;
    v[0] = f2bf(f0.x * SCALE); v[1] = f2bf(f0.y * SCALE);
    v[2] = f2bf(f0.z * SCALE); v[3] = f2bf(f0.w * SCALE);
    v[4] = f2bf(f1.x * SCALE); v[5] = f2bf(f1.y * SCALE);
    v[6] = f2bf(f1.z * SCALE); v[7] = f2bf(f1.w * SCALE);
    *(ushort8v*)(Hb + t * 8) = v;
}

// ---------------------------------------------------------------------------
// Kernel B: fused hash-pair + cls. One 128x128 upper-tri tile per block.
// MFMA fragments loaded DIRECTLY from global bf16 (8 contiguous bf16/lane =
// one dwordx4); no LDS tiles, no conversion, no staging barrier.
// ---------------------------------------------------------------------------
__global__ __launch_bounds__(256) void hash_cls_kernel(const unsigned short* __restrict__ HB,
                                                       const float* __restrict__ X,
                                                       const int* __restrict__ tgt,
                                                       double* __restrict__ ws) {
    __shared__ int   tl[256];      // [0,128) = tI, [128,256) = tJ
    __shared__ float red[16];

    const int tid = threadIdx.x;
    const int p = blockIdx.x;

    // map linear block id -> (ti, tj) with ti <= tj
    int ti;
    {
        float disc = (2.0f * NT + 1.0f) * (2.0f * NT + 1.0f) - 8.0f * (float)p;
        ti = (int)(((2.0f * NT + 1.0f) - sqrtf(disc)) * 0.5f);
        if (ti < 0) ti = 0;
        if (ti >= NT) ti = NT - 1;
        while (ti > 0 && (ti * NT - ti * (ti - 1) / 2) > p) ti--;
        while ((ti + 1) * NT - (ti + 1) * ti / 2 <= p) ti++;
    }
    const int base = ti * NT - ti * (ti - 1) / 2;
    const int tj = ti + (p - base);
    const int i0 = ti * TILE, j0 = tj * TILE;
    const bool diag = (ti == tj);

    tl[tid] = (tid < 128) ? tgt[i0 + tid] : tgt[j0 + tid - 128];

    const int lane = tid & 63, wave = tid >> 6;
    const int wr = wave >> 1, wc = wave & 1;   // 2x2 wave grid, 64x64 each
    const int lrow = lane & 31, hi = lane >> 5;

    // fragment base pointers: row-major bf16, 8 contiguous elems per lane
    const ushort8v* pA0 = (const ushort8v*)(HB + (size_t)(i0 + wr * 64 +      lrow) * BITS + hi * 8);
    const ushort8v* pA1 = (const ushort8v*)(HB + (size_t)(i0 + wr * 64 + 32 + lrow) * BITS + hi * 8);
    const ushort8v* pB0 = (const ushort8v*)(HB + (size_t)(j0 + wc * 64 +      lrow) * BITS + hi * 8);
    const ushort8v* pB1 = (const ushort8v*)(HB + (size_t)(j0 + wc * 64 + 32 + lrow) * BITS + hi * 8);

    bf16x8 fa0[4], fa1[4], fb0[4], fb1[4];
#pragma unroll
    for (int ks = 0; ks < 4; ++ks) {     // chunk = ks*2 + hi -> offset ks*32B
        fa0[ks] = __builtin_bit_cast(bf16x8, pA0[ks * 2]);
        fa1[ks] = __builtin_bit_cast(bf16x8, pA1[ks * 2]);
        fb0[ks] = __builtin_bit_cast(bf16x8, pB0[ks * 2]);
        fb1[ks] = __builtin_bit_cast(bf16x8, pB1[ks * 2]);
    }

    f32x16 c00, c01, c10, c11;
#pragma unroll
    for (int e = 0; e < 16; ++e) { c00[e] = 0.f; c01[e] = 0.f; c10[e] = 0.f; c11[e] = 0.f; }

#pragma unroll
    for (int ks = 0; ks < 4; ++ks) {
        c00 = __builtin_amdgcn_mfma_f32_32x32x16_bf16(fa0[ks], fb0[ks], c00, 0, 0, 0);
        c01 = __builtin_amdgcn_mfma_f32_32x32x16_bf16(fa0[ks], fb1[ks], c01, 0, 0, 0);
        c10 = __builtin_amdgcn_mfma_f32_32x32x16_bf16(fa1[ks], fb0[ks], c10, 0, 0, 0);
        c11 = __builtin_amdgcn_mfma_f32_32x32x16_bf16(fa1[ks], fb1[ks], c11, 0, 0, 0);
    }
    __syncthreads();   // tl[] ready for epilogue

    // acc element (reg r) -> local row = (r&3) + 8*(r>>2) + 4*hi, col = lane&31
    float s_all = 0.f, s_same = 0.f, t_same = 0.f;
    const int tc0 = tl[128 + wc * 64 +      lrow];
    const int tc1 = tl[128 + wc * 64 + 32 + lrow];

    if (!diag) {
#pragma unroll
        for (int it = 0; it < 2; ++it) {
            const f32x16& C0 = it ? c10 : c00;
            const f32x16& C1 = it ? c11 : c01;
#pragma unroll
            for (int r = 0; r < 16; ++r) {
                const int tr = tl[wr * 64 + it * 32 + (r & 3) + 8 * (r >> 2) + 4 * hi];
                float t0 = C0[r], t1 = C1[r];          // theta * log2e
                float l0 = __log2f(1.f + exp2f(t0));   // softplus / ln2
                float l1 = __log2f(1.f + exp2f(t1));
                s_all += l0 + l1;
                float m0 = (tr == tc0) ? 1.f : 0.f;
                float m1 = (tr == tc1) ? 1.f : 0.f;
                s_same = fmaf(m0, l0, s_same); s_same = fmaf(m1, l1, s_same);
                t_same = fmaf(m0, t0, t_same); t_same = fmaf(m1, t1, t_same);
            }
        }
    } else {
        const int lc0 = wc * 64 + lrow;
        const int lc1 = lc0 + 32;
#pragma unroll
        for (int it = 0; it < 2; ++it) {
            const f32x16& C0 = it ? c10 : c00;
            const f32x16& C1 = it ? c11 : c01;
#pragma unroll
            for (int r = 0; r < 16; ++r) {
                const int lr = wr * 64 + it * 32 + (r & 3) + 8 * (r >> 2) + 4 * hi;
                const int tr = tl[lr];
                float t0 = C0[r], t1 = C1[r];
                float l0 = __log2f(1.f + exp2f(t0));
                float l1 = __log2f(1.f + exp2f(t1));
                bool v0 = lc0 > lr, v1 = lc1 > lr;
                s_all += (v0 ? l0 : 0.f) + (v1 ? l1 : 0.f);
                float m0 = (v0 && tr == tc0) ? 1.f : 0.f;
                float m1 = (v1 && tr == tc1) ? 1.f : 0.f;
                s_same = fmaf(m0, l0, s_same); s_same = fmaf(m1, l1, s_same);
                t_same = fmaf(m0, t0, t_same); t_same = fmaf(m1, t1, t_same);
            }
        }
    }

#pragma unroll
    for (int d = 32; d > 0; d >>= 1) {
        s_all  += __shfl_xor(s_all,  d, 64);
        s_same += __shfl_xor(s_same, d, 64);
        t_same += __shfl_xor(t_same, d, 64);
    }
    if (lane == 0) { red[wave] = s_all; red[4 + wave] = s_same; red[8 + wave] = t_same; }

    // fused cls: block p handles rows 4p .. 4p+3, one row per wave
    {
        const int row = p * 4 + wave;
        float nll = 0.f;
        if (row < NPTS) {
            const float* x = X + (size_t)row * NCLS;
            float x1 = x[lane];
            float x2 = (lane + 64 < NCLS) ? x[lane + 64] : -INFINITY;
            float m = fmaxf(x1, x2);
#pragma unroll
            for (int d = 32; d > 0; d >>= 1) m = fmaxf(m, __shfl_xor(m, d, 64));
            float e = __expf(x1 - m) + ((lane + 64 < NCLS) ? __expf(x2 - m) : 0.f);
#pragma unroll
            for (int d = 32; d > 0; d >>= 1) e += __shfl_xor(e, d, 64);
            if (lane == 0) nll = m + __logf(e) - x[tgt[row]];
        }
        if (lane == 0) red[12 + wave] = nll;
    }
    __syncthreads();
    if (tid == 0) {
        ws[p]              = (double)red[0]  + (double)red[1]  + (double)red[2]  + (double)red[3];
        ws[NPAIRS + p]     = (double)red[4]  + (double)red[5]  + (double)red[6]  + (double)red[7];
        ws[2 * NPAIRS + p] = (double)red[8]  + (double)red[9]  + (double)red[10] + (double)red[11];
        ws[WS_CLS + p]     = (double)red[12] + (double)red[13] + (double)red[14] + (double)red[15];
    }
}

// ---------------------------------------------------------------------------
// Finalize: histogram -> S0/S1 weights; reduce partials in double; ln2 folds
// applied here; write the 3 output scalars.
// ---------------------------------------------------------------------------
__global__ __launch_bounds__(256) void final_kernel(const int* __restrict__ tgt,
                                                    const double* __restrict__ ws,
                                                    float* __restrict__ out) {
    __shared__ int hist[NCLS];
    __shared__ double r0[256], r1[256], r2[256], rc[256];
    const int tid = threadIdx.x;

    for (int i = tid; i < NCLS; i += 256) hist[i] = 0;
    __syncthreads();
    for (int i = tid; i < NPTS; i += 256) atomicAdd(&hist[tgt[i]], 1);
    __syncthreads();

    double a = 0.0, s = 0.0, t = 0.0, c = 0.0;
    for (int i = tid; i < NPAIRS; i += 256) {
        a += ws[i];
        s += ws[NPAIRS + i];
        t += ws[2 * NPAIRS + i];
        c += ws[WS_CLS + i];
    }
    r0[tid] = a; r1[tid] = s; r2[tid] = t; rc[tid] = c;
    __syncthreads();
    for (int sdt = 128; sdt > 0; sdt >>= 1) {
        if (tid < sdt) {
            r0[tid] += r0[tid + sdt];
            r1[tid] += r1[tid + sdt];
            r2[tid] += r2[tid + sdt];
            rc[tid] += rc[tid + sdt];
        }
        __syncthreads();
    }

    if (tid == 0) {
        double n_pos = 0.0;
        for (int k = 0; k < NCLS; k++) {
            double cc = (double)hist[k];
            n_pos += cc * cc;
        }
        const double Nd = (double)NPTS;
        double S1 = n_pos - Nd;
        double S0 = Nd * Nd - n_pos;
        if (S0 == 0.0) S0 = 1.0;
        if (S1 == 0.0) S1 = 1.0;
        const double S = S0 + S1;
        // partials are in log2/log2e units -> one ln2 factor here
        const double sum_lower = ((S / S0) * (r0[0] - r1[0]) + (S / S1) * (r1[0] - r2[0])) * LN2;
        const double count = Nd * (Nd - 1.0) * 0.5;
        const double hash_loss = sum_lower / count;
        const double cls_loss  = rc[0] / Nd;
        const double loss = 1.0 * cls_loss + 0.01 * hash_loss;
        out[0] = (float)hash_loss;
        out[1] = (float)cls_loss;
        out[2] = (float)loss;
    }
}

// ---------------------------------------------------------------------------
extern "C" void kernel_launch(void* const* d_in, const int* in_sizes, int n_in,
                              void* d_out, int out_size, void* d_ws, size_t ws_size,
                              hipStream_t stream) {
    const float* H   = (const float*)d_in[0];   // hash_out [8192,64]
    const float* X   = (const float*)d_in[1];   // cls_out  [8192,101]
    const int*   tgt = (const int*)d_in[2];     // target   [8192]
    float* out = (float*)d_out;

    unsigned short* Hb = (unsigned short*)d_ws;
    double* wsd = (double*)((char*)d_ws + HBF_BYTES);

    conv_kernel<<<(NPTS * BITS) / (256 * 8), 256, 0, stream>>>(H, Hb);
    hash_cls_kernel<<<NPAIRS, 256, 0, stream>>>(Hb, X, tgt, wsd);
    final_kernel<<<1, 256, 0, stream>>>(tgt, wsd, out);
}